// Round 6
// baseline (394.241 us; speedup 1.0000x reference)
//
#include <hip/hip_runtime.h>
#include <math.h>

// EntNet forward on MI355X.
// Sizes: VOC=32000, MEM=128, NSLOTS=20, NSENT=128, MAXLEN=32, QLEN=16, ANSLEN=8, B=64
//
// R20: operand-swapped main MFMA. D'[n][b] = mfma(A=Uw-frag, B=state-frag)
// uses the IDENTICAL LDS state layout + ds_read pattern (A/B frag layouts
// are symmetric), but the C layout becomes col=lane=b, rows=n:
// each thread owns ONE batch row b and 16 n-values (4 groups of 4).
//  - gate dot(s_t, mem[b]) becomes a per-thread partial computed in the
//    update phase from fp32 x registers (+1 shfl_xor(32), 1 LDS write to
//    gdp[b][nt2]); next step's g = sigmoid of a 1x ds_read_b128 sum —
//    the entire gate PHASE, g_l round trip, and its LDS traffic vanish.
//    B2->B1 segment now contains only: inv_s, per-thread g (~15 ops),
//    frag reads + MFMA issue.
//  - AB state writes: 16x ds_write_b16 -> 4x ds_write_b64 (consecutive n).
//  - wsv: 16 scalar loads -> 4x dwordx4; ubv per-thread 16-vec loaded once;
//    h_out 4x dwordx4 stores.
// R17/R18b/R19 lesson encoded: no serial all-wave phase between barriers.

typedef __attribute__((ext_vector_type(8)))  short bf16x8;
typedef __attribute__((ext_vector_type(16))) float f32x16;

__device__ __forceinline__ unsigned short f2bh(float x) {   // f32 -> bf16 RNE
    unsigned int u = __float_as_uint(x);
    u += 0x7FFFu + ((u >> 16) & 1u);
    return (unsigned short)(u >> 16);
}
// u32 holding two bf16 (little-endian): low 16 = element 2i, high = 2i+1
__device__ __forceinline__ float blo(unsigned int w) { return __uint_as_float(w << 16); }
__device__ __forceinline__ float bhi(unsigned int w) { return __uint_as_float(w & 0xFFFF0000u); }
// pack two f32 -> u32 of two bf16 (truncation; fp32 recurrence carries precision)
__device__ __forceinline__ unsigned int packtr(float lo, float hi) {
    return (__float_as_uint(lo) >> 16) | (__float_as_uint(hi) & 0xFFFF0000u);
}

// butterfly add with quad-local DPP (xor1: quad_perm[1,0,3,2]=0xB1,
// xor2: quad_perm[2,3,0,1]=0x4E) — ~4cy vs ~35cy ds_swizzle.
__device__ __forceinline__ float dpp_xor1_add(float x) {
    int y = __builtin_amdgcn_update_dpp(0, __float_as_int(x), 0xB1, 0xF, 0xF, true);
    return x + __int_as_float(y);
}
__device__ __forceinline__ float dpp_xor2_add(float x) {
    int y = __builtin_amdgcn_update_dpp(0, __float_as_int(x), 0x4E, 0xF, 0xF, true);
    return x + __int_as_float(y);
}

// LDS-only workgroup barrier: waits own DS ops, does NOT drain vmcnt, so
// prefetched global loads (private register results) stay in flight.
#define LDS_BARRIER() do {                                   \
    asm volatile("s_waitcnt lgkmcnt(0)" ::: "memory");       \
    __builtin_amdgcn_s_barrier();                            \
    asm volatile("" ::: "memory");                           \
} while (0)

// ---------------------------------------------------------------- prep
__global__ __launch_bounds__(128) void prep_kernel(
    const int* __restrict__ ids, const int* __restrict__ ques, const int* __restrict__ ans,
    const float* __restrict__ E, const float* __restrict__ Ww, const float* __restrict__ Wb,
    const float* __restrict__ Vw, const float* __restrict__ Vb, const float* __restrict__ skeys,
    unsigned short* __restrict__ sTb, float* __restrict__ WsT, float* __restrict__ vkey,
    float* __restrict__ qv, float* __restrict__ a1v, float* __restrict__ a2v,
    float* __restrict__ SK)
{
    const int bi  = blockIdx.x;
    const int tid = threadIdx.x;   // 128
    __shared__ float s_l[8][132];
    __shared__ float sk_l[20 * 132];
    __shared__ float k_l[128];
    if (bi < 1024) {
        const int b = bi >> 4;
        const int g = bi & 15;
        for (int r = tid; r < 2560; r += 128) sk_l[(r >> 7) * 132 + (r & 127)] = skeys[r];
        for (int tt = 0; tt < 8; ++tt) {
            const int t     = g * 8 + tt;
            const int token = ids[b * 4096 + t];
            const float v   = E[token * 128 + tid];
            s_l[tt][tid] = v;
            sTb[(t * 64 + b) * 128 + tid] = f2bh(v);   // bf16 plane (t, b, m)
        }
        __syncthreads();
        // Ws rows
        float acc[8];
        const float wbn = Wb[tid];
        #pragma unroll
        for (int i = 0; i < 8; ++i) acc[i] = wbn;
        const float4* wrow = (const float4*)(Ww + tid * 128);
        for (int m4 = 0; m4 < 32; ++m4) {
            const float4 w = wrow[m4];
            #pragma unroll
            for (int tt = 0; tt < 8; ++tt) {
                acc[tt] += s_l[tt][m4*4+0]*w.x + s_l[tt][m4*4+1]*w.y
                         + s_l[tt][m4*4+2]*w.z + s_l[tt][m4*4+3]*w.w;
            }
        }
        for (int tt = 0; tt < 8; ++tt)
            WsT[((g*8+tt) * 64 + b) * 128 + tid] = acc[tt];     // layout (t, b, n)
        // SK[j][t][b] = dot(s_t[b], skeys[j])  (gate key-dot, hoisted from scan)
        for (int idx = tid; idx < 160; idx += 128) {
            const int tt = idx / 20;
            const int jj = idx - tt * 20;
            float d = 0.f;
            for (int m = 0; m < 128; ++m) d += s_l[tt][m] * sk_l[jj * 132 + m];
            SK[(jj * 128 + (g*8 + tt)) * 64 + b] = d;
        }
    } else if (bi < 1044) {
        const int j = bi - 1024;
        k_l[tid] = skeys[j * 128 + tid];
        __syncthreads();
        float acc = Vb[tid];
        const float4* vrow = (const float4*)(Vw + tid * 128);
        for (int m4 = 0; m4 < 32; ++m4) {
            const float4 w = vrow[m4];
            acc += k_l[m4*4]*w.x + k_l[m4*4+1]*w.y + k_l[m4*4+2]*w.z + k_l[m4*4+3]*w.w;
        }
        vkey[j * 128 + tid] = acc;
    } else {
        const int b = bi - 1044;
        float sq = 0.f, s1 = 0.f, s2 = 0.f;
        for (int i = 0; i < 16; ++i) sq += E[ques[b*16+i] * 128 + tid];
        for (int i = 0; i < 8;  ++i) s1 += E[ans[(b*8+i)*2+0] * 128 + tid];
        for (int i = 0; i < 8;  ++i) s2 += E[ans[(b*8+i)*2+1] * 128 + tid];
        qv [b*128+tid] = sq * (1.f/16.f);
        a1v[b*128+tid] = s1 * 0.125f;
        a2v[b*128+tid] = s2 * 0.125f;
    }
}

// ---------------------------------------------------------------- scan
// One block per slot j. 512 threads = 8 waves, 2 waves/SIMD.
// Operand-swapped MFMA: D'[n][b] = mfma(A=Uw rows n, B=state cols b).
// Wave (bt2=wave&1, nt2=wave>>1); lane: b = bt2*32+l32 (owned batch row),
// n-values = nt2*32 + 4q + (r&3) + 8*(r>>2)  (4 groups of 4 consecutive).
// 2 lgkm-only barriers/step. gate = per-thread (gdp partials via B2).
__global__ __launch_bounds__(512, 1) void scan_kernel(
    const unsigned short* __restrict__ sTb, const float* __restrict__ WsT,
    const float* __restrict__ vkey, const float* __restrict__ Uw,
    const float* __restrict__ Ub, const float* __restrict__ SK,
    float* __restrict__ h_out)
{
    __shared__ unsigned short AB[64 * 136];   // bf16 state [b][m], stride 136
    __shared__ float gdp[64 * 4];             // gate-dot partials [b][nt2]
    __shared__ float wred[8];

    const int j    = blockIdx.x;
    const int tid  = threadIdx.x;        // 512
    const int wave = tid >> 6;           // 0..7
    const int lane = tid & 63;
    const int l32  = lane & 31;
    const int q    = lane >> 5;          // 0..1
    const int bt2  = wave & 1;
    const int nt2  = wave >> 1;
    const int b    = bt2 * 32 + l32;     // owned batch row (D' col)
    const int n0   = nt2 * 32 + 4 * q;   // n base; n(r) = n0 + (r&3) + 8*(r>>2)
    const int nrow = nt2 * 32 + l32;     // Uw row for A-frag

    // ---- one-time: Uw A-fragments -> 32 VGPRs (bf16 RNE) ----
    bf16x8 b_h[8];
    {
        const int k0 = q * 8;
        #pragma unroll
        for (int kc = 0; kc < 8; ++kc) {
            const float4* src = (const float4*)(Uw + nrow * 128 + kc * 16 + k0);
            const float4 v0 = src[0], v1 = src[1];
            const float xs[8] = {v0.x,v0.y,v0.z,v0.w, v1.x,v1.y,v1.z,v1.w};
            #pragma unroll
            for (int e = 0; e < 8; ++e) b_h[kc][e] = (short)f2bh(xs[e]);
        }
    }

    // ---- one-time: per-thread bias vector ubv[r] = Ub[n(r)] + vkey[j][n(r)] ----
    float ubv[16];
    #pragma unroll
    for (int g4 = 0; g4 < 4; ++g4) {
        const float4 u4 = *(const float4*)(Ub + n0 + 8 * g4);
        const float4 v4 = *(const float4*)(vkey + j * 128 + n0 + 8 * g4);
        ubv[g4*4+0] = u4.x + v4.x;  ubv[g4*4+1] = u4.y + v4.y;
        ubv[g4*4+2] = u4.z + v4.z;  ubv[g4*4+3] = u4.w + v4.w;
    }

    // ---- per-thread invariant byte offsets ----
    const char* SKj = (const char*)SK + (size_t)j * 32768;
    const unsigned wbyte = (unsigned)((b * 128 + n0) * 4);   // into WsT (+t*32768, +32*g)
    const unsigned sbyte = (unsigned)(b * 256 + n0 * 2);     // into sTb (+t*16384, +16*g)

    for (int i = tid; i < 64 * 136 / 2; i += 512) ((unsigned int*)AB)[i] = 0u;
    if (tid < 256) gdp[tid] = 0.f;

    float xprev[16];
    #pragma unroll
    for (int r = 0; r < 16; ++r) xprev[r] = 0.f;

    // ---- prefetched globals ----
    float4 wA, wB, wC, wD;     // Ws[t][b][n-groups]
    uint2  sA, sB, sC, sD;     // s_{t+1}[b][n-groups] as bf16 pairs
    float  skv;                // SK[j][t][b]
    {
        const char* pW = (const char*)WsT + wbyte;
        wA = *(const float4*)(pW);      wB = *(const float4*)(pW + 32);
        wC = *(const float4*)(pW + 64); wD = *(const float4*)(pW + 96);
        const char* pS = (const char*)sTb + 16384 + sbyte;   // t=1
        sA = *(const uint2*)(pS);      sB = *(const uint2*)(pS + 16);
        sC = *(const uint2*)(pS + 32); sD = *(const uint2*)(pS + 48);
        skv = *(const float*)(SKj + b * 4);
    }
    __syncthreads();

    float inv_s = 1.f;                   // true mem = inv_s * state

    for (int t = 0; t < 128; ++t) {
        const int tn  = (t < 127) ? t + 1 : 127;
        const int tn2 = (t < 126) ? t + 2 : 127;

        // ---- gate: thread-local. gdp published at prev B2. ----
        const float4 gd4 = *(const float4*)(gdp + b * 4);
        const float gsum = (gd4.x + gd4.y) + (gd4.z + gd4.w);
        const float ge   = __expf(-fmaf(inv_s, gsum, skv));
        const float g    = __builtin_amdgcn_rcpf(1.f + ge);   // fast sigmoid

        // ---- bias fold (wsv vmcnt satisfied long ago) ----
        float wsvu[16];
        wsvu[0]=wA.x+ubv[0];  wsvu[1]=wA.y+ubv[1];  wsvu[2]=wA.z+ubv[2];  wsvu[3]=wA.w+ubv[3];
        wsvu[4]=wB.x+ubv[4];  wsvu[5]=wB.y+ubv[5];  wsvu[6]=wB.z+ubv[6];  wsvu[7]=wB.w+ubv[7];
        wsvu[8]=wC.x+ubv[8];  wsvu[9]=wC.y+ubv[9];  wsvu[10]=wC.z+ubv[10]; wsvu[11]=wC.w+ubv[11];
        wsvu[12]=wD.x+ubv[12]; wsvu[13]=wD.y+ubv[13]; wsvu[14]=wD.z+ubv[14]; wsvu[15]=wD.w+ubv[15];

        // ---- main MFMA (operand-swapped): D'[n][b] ----
        f32x16 acc0 = {0.f,0.f,0.f,0.f,0.f,0.f,0.f,0.f,
                       0.f,0.f,0.f,0.f,0.f,0.f,0.f,0.f};
        f32x16 acc1 = acc0;
        const unsigned short* arow = AB + b * 136 + q * 8;
        #pragma unroll
        for (int kc = 0; kc < 8; ++kc) {
            const bf16x8 a = *(const bf16x8*)(arow + kc * 16);   // state frag (B-op)
            if (kc & 1) acc1 = __builtin_amdgcn_mfma_f32_32x32x16_bf16(b_h[kc], a, acc1, 0, 0, 0);
            else        acc0 = __builtin_amdgcn_mfma_f32_32x32x16_bf16(b_h[kc], a, acc0, 0, 0, 0);
        }
        acc0 += acc1;
        LDS_BARRIER();   // B1: frag + gdp reads complete (MFMA results pending OK)

        // ---- update: x = inv_s*xprev + g*relu(inv_s*acc + ws+ub+vk) ----
        // also: gate partial for t+1 (fp32 x . bf16 s_{t+1}) and ssq.
        float xv[16];
        float sq0 = 0.f, sq1 = 0.f;
        float gp0 = 0.f, gp1 = 0.f;
        const float sp[16] = {
            blo(sA.x), bhi(sA.x), blo(sA.y), bhi(sA.y),
            blo(sB.x), bhi(sB.x), blo(sB.y), bhi(sB.y),
            blo(sC.x), bhi(sC.x), blo(sC.y), bhi(sC.y),
            blo(sD.x), bhi(sD.x), blo(sD.y), bhi(sD.y)};
        #pragma unroll
        for (int r = 0; r < 16; ++r) {
            float hr = fmaf(inv_s, acc0[r], wsvu[r]);
            hr = fmaxf(hr, 0.f);
            const float x = fmaf(inv_s, xprev[r], g * hr);
            xprev[r] = x; xv[r] = x;
            if (r & 1) { sq1 = fmaf(x, x, sq1); gp1 = fmaf(x, sp[r], gp1); }
            else       { sq0 = fmaf(x, x, sq0); gp0 = fmaf(x, sp[r], gp0); }
        }
        // packed state writes: 4x ds_write_b64 (consecutive n)
        {
            unsigned int* dst = (unsigned int*)(AB + b * 136 + n0);
            *(uint2*)(dst +  0) = (uint2){packtr(xv[0],  xv[1]),  packtr(xv[2],  xv[3])};
            *(uint2*)(dst +  4) = (uint2){packtr(xv[4],  xv[5]),  packtr(xv[6],  xv[7])};
            *(uint2*)(dst +  8) = (uint2){packtr(xv[8],  xv[9]),  packtr(xv[10], xv[11])};
            *(uint2*)(dst + 12) = (uint2){packtr(xv[12], xv[13]), packtr(xv[14], xv[15])};
        }

        // ---- prefetch (lgkm-only barriers keep these in flight) ----
        {
            const char* pW = (const char*)WsT + (size_t)tn * 32768 + wbyte;
            wA = *(const float4*)(pW);      wB = *(const float4*)(pW + 32);
            wC = *(const float4*)(pW + 64); wD = *(const float4*)(pW + 96);
            const char* pS = (const char*)sTb + (size_t)tn2 * 16384 + sbyte;
            sA = *(const uint2*)(pS);      sB = *(const uint2*)(pS + 16);
            sC = *(const uint2*)(pS + 32); sD = *(const uint2*)(pS + 48);
            skv = *(const float*)(SKj + (size_t)tn * 256 + b * 4);
        }

        // ---- gate partial publish: q-halves combine, one write per (wave,b) ----
        float gp = gp0 + gp1;
        gp += __shfl_xor(gp, 32, 64);
        if (q == 0) gdp[b * 4 + nt2] = gp;

        // ---- ssq reduce (proven chain) + B2 ----
        float ssq = sq0 + sq1;
        ssq = dpp_xor1_add(ssq);
        ssq = dpp_xor2_add(ssq);
        ssq += __shfl_xor(ssq, 4, 64);
        ssq += __shfl_xor(ssq, 8, 64);
        ssq += __shfl_xor(ssq, 16, 64);
        ssq += __shfl_xor(ssq, 32, 64);
        if (lane == 0) wred[wave] = ssq;
        LDS_BARRIER();   // B2: AB/gdp/wred writes visible
        const float4 w0 = *(const float4*)(wred);
        const float4 w1 = *(const float4*)(wred + 4);
        inv_s = __builtin_amdgcn_rsqf(w0.x+w0.y+w0.z+w0.w + w1.x+w1.y+w1.z+w1.w);
    }

    // ---- h = inv_s * state, layout (b, j, m): 4x dwordx4 stores ----
    float* hb = h_out + ((size_t)b * 20 + j) * 128 + n0;
    #pragma unroll
    for (int g4 = 0; g4 < 4; ++g4) {
        float4 o;
        o.x = inv_s * xprev[g4*4+0]; o.y = inv_s * xprev[g4*4+1];
        o.z = inv_s * xprev[g4*4+2]; o.w = inv_s * xprev[g4*4+3];
        *(float4*)(hb + 8 * g4) = o;
    }
}

// ---------------------------------------------------------------- final
__global__ __launch_bounds__(128) void final_kernel(
    const float* __restrict__ h, const float* __restrict__ qv,
    const float* __restrict__ a1v, const float* __restrict__ a2v,
    const float* __restrict__ Hw, const float* __restrict__ Hb,
    float* __restrict__ out)
{
    const int b   = blockIdx.x;
    const int tid = threadIdx.x;    // 128
    __shared__ float hb[20][128];
    __shared__ float ql[128];
    __shared__ float ul[128];
    __shared__ float pl[20];
    __shared__ float lgt[20];
    __shared__ float red1[2], red2[2];

    for (int jj = 0; jj < 20; ++jj) hb[jj][tid] = h[(b*20+jj)*128 + tid];
    ql[tid] = qv[b*128 + tid];
    __syncthreads();
    if (tid < 20) {
        float d = 0.f;
        for (int m = 0; m < 128; ++m) d += hb[tid][m] * ql[m];
        lgt[tid] = d;
    }
    __syncthreads();
    if (tid == 0) {
        float mx = lgt[0];
        for (int jj = 1; jj < 20; ++jj) mx = fmaxf(mx, lgt[jj]);
        float s = 0.f;
        for (int jj = 0; jj < 20; ++jj) { const float e = expf(lgt[jj]-mx); pl[jj] = e; s += e; }
        const float is = 1.f / s;
        for (int jj = 0; jj < 20; ++jj) pl[jj] *= is;
    }
    __syncthreads();
    float u = 0.f;
    for (int jj = 0; jj < 20; ++jj) u += pl[jj] * hb[jj][tid];
    ul[tid] = u;
    __syncthreads();
    float acc = ql[tid] + Hb[tid];
    const float4* hwr = (const float4*)(Hw + tid*128);
    for (int m4 = 0; m4 < 32; ++m4) {
        const float4 w = hwr[m4];
        acc += ul[m4*4]*w.x + ul[m4*4+1]*w.y + ul[m4*4+2]*w.z + ul[m4*4+3]*w.w;
    }
    const float r  = fmaxf(acc, 0.f);
    float y1 = r * a1v[b*128+tid];
    float y2 = r * a2v[b*128+tid];
    #pragma unroll
    for (int mask = 1; mask < 64; mask <<= 1) {
        y1 += __shfl_xor(y1, mask, 64);
        y2 += __shfl_xor(y2, mask, 64);
    }
    if ((tid & 63) == 0) { red1[tid>>6] = y1; red2[tid>>6] = y2; }
    __syncthreads();
    if (tid == 0) {
        const float z1 = red1[0] + red1[1];
        const float z2 = red2[0] + red2[1];
        const float mx = fmaxf(z1, z2);
        const float e1 = expf(z1-mx), e2 = expf(z2-mx);
        const float s  = e1 + e2;
        out[b*2+0] = e1 / s;
        out[b*2+1] = e2 / s;
    }
}

// ---------------------------------------------------------------- launch
extern "C" void kernel_launch(void* const* d_in, const int* in_sizes, int n_in,
                              void* d_out, int out_size, void* d_ws, size_t ws_size,
                              hipStream_t stream)
{
    const int*   ids  = (const int*)  d_in[0];
    const int*   ques = (const int*)  d_in[1];
    const int*   ans  = (const int*)  d_in[2];
    const float* E    = (const float*)d_in[3];
    const float* Uw   = (const float*)d_in[4];
    const float* Ubv  = (const float*)d_in[5];
    const float* Vw   = (const float*)d_in[6];
    const float* Vb   = (const float*)d_in[7];
    const float* Ww   = (const float*)d_in[8];
    const float* Wb   = (const float*)d_in[9];
    const float* sk   = (const float*)d_in[10];
    const float* Hw   = (const float*)d_in[11];
    const float* Hb   = (const float*)d_in[12];

    // workspace (floats): sTb bf16[1048576] = 524288 floats | WsT 1048576 |
    //   vkey 2560 | qv/a1v/a2v 3*8192 | h 163840 | SK 163840   (~7.7 MB)
    float* ws   = (float*)d_ws;
    unsigned short* sTb = (unsigned short*)ws;        // 1048576 ushort = 524288 floats
    float* WsT  = ws    + 524288;
    float* vkey = WsT   + 1048576;
    float* qv   = vkey  + 2560;
    float* a1v  = qv    + 8192;
    float* a2v  = a1v   + 8192;
    float* h    = a2v   + 8192;
    float* SK   = h     + 163840;

    prep_kernel<<<1108, 128, 0, stream>>>(ids, ques, ans, E, Ww, Wb, Vw, Vb, sk,
                                          sTb, WsT, vkey, qv, a1v, a2v, SK);
    scan_kernel<<<20, 512, 0, stream>>>(sTb, WsT, vkey, Uw, Ubv, SK, h);
    final_kernel<<<64, 128, 0, stream>>>(h, qv, a1v, a2v, Hw, Hb, (float*)d_out);
}